// Round 1
// baseline (2059.147 us; speedup 1.0000x reference)
//
#include <hip/hip_runtime.h>
#include <cmath>

// DeepSeek V2 MoE (fp32 baseline, correctness-first).
// Structure: routing -> token lists -> gathered gate/up GEMM -> down GEMM w/ scatter.
// Round 1 plan: fp32 vector FMA everywhere (no fp32 MFMA on CDNA4). Next round:
// swap GEMM cores to bf16 MFMA as an isolated numerics experiment.

#define HIDN   1024
#define NEXP   64
#define INTERD 704
#define TOPK   6
#define NGRP   8
#define TOPG   4
#define NTOK   2048
#define SHINTER 1408     // INTER * N_SHARED
#define RSCALE 2.5f
#define FMAXV  3.402823466e38f

// ---- workspace layout (bytes) ----
#define WS_CNT 0                               // 64 int
#define WS_OFF 1024                            // 64 int
#define WS_TOK 4096                            // 64*2048 int  (512KB)
#define WS_W   (4096 + 64*2048*4)              // 64*2048 float (512KB)
#define WS_H   (4096 + 2*64*2048*4)            // (12288+64) rows * 704 f32
#define WS_HS  (WS_H + (12288+64)*704*4)       // 2048 * 1408 f32
// total ~47.4 MB

__global__ __launch_bounds__(64) void zero_cnt_kernel(int* cnt) {
    cnt[threadIdx.x] = 0;
}

// ---------------- routing: logits + grouped top-k, build expert token lists ----------------
__global__ __launch_bounds__(64) void routing_kernel(
    const float* __restrict__ x, const float* __restrict__ gw,
    const float* __restrict__ bias, int* __restrict__ cnt,
    int* __restrict__ tl_tok, float* __restrict__ tl_w)
{
    __shared__ float xs[HIDN];
    __shared__ float ssc[NEXP];     // biased score
    __shared__ float sscore[NEXP];  // unbiased sigmoid score
    const int t = blockIdx.x;
    const int tid = threadIdx.x;
    for (int i = tid; i < HIDN; i += 64) xs[i] = x[(size_t)t*HIDN + i];
    __syncthreads();

    // each thread computes one expert logit
    const float* gwe = gw + (size_t)tid*HIDN;
    float acc = 0.f;
    for (int k = 0; k < HIDN; k += 4) {
        float4 g = *(const float4*)(gwe + k);
        acc += xs[k]*g.x + xs[k+1]*g.y + xs[k+2]*g.z + xs[k+3]*g.w;
    }
    float score = 1.f/(1.f + expf(-acc));
    sscore[tid] = score;
    ssc[tid] = score + bias[tid];
    __syncthreads();

    if (tid == 0) {
        // group scores: sum of top-2 biased scores per group of 8
        float gsc[NGRP];
        #pragma unroll
        for (int g = 0; g < NGRP; ++g) {
            float m1 = -FMAXV, m2 = -FMAXV;
            #pragma unroll
            for (int i = 0; i < 8; ++i) {
                float v = ssc[g*8 + i];
                if (v > m1) { m2 = m1; m1 = v; }
                else if (v > m2) { m2 = v; }
            }
            gsc[g] = m1 + m2;
        }
        // top-4 groups (strict >, first index wins = lax.top_k tie rule)
        unsigned gselmask = 0;
        #pragma unroll
        for (int it = 0; it < TOPG; ++it) {
            float best = -FMAXV; int bg = 0;
            #pragma unroll
            for (int g = 0; g < NGRP; ++g) {
                if ((gselmask >> g) & 1u) continue;
                if (gsc[g] > best) { best = gsc[g]; bg = g; }
            }
            gselmask |= (1u << bg);
        }
        // top-6 experts among allowed groups
        unsigned long long taken = 0ull;
        int ids[TOPK]; float w[TOPK]; float wsum = 0.f;
        #pragma unroll
        for (int it = 0; it < TOPK; ++it) {
            float best = -FMAXV; int be = 0;
            for (int e = 0; e < NEXP; ++e) {
                if (!((gselmask >> (e >> 3)) & 1u)) continue;
                if ((taken >> e) & 1ull) continue;
                float v = ssc[e];
                if (v > best) { best = v; be = e; }
            }
            taken |= (1ull << be);
            ids[it] = be;
            w[it] = sscore[be];
            wsum += w[it];
        }
        float inv = 1.f / wsum;
        #pragma unroll
        for (int s = 0; s < TOPK; ++s) {
            int e = ids[s];
            int pos = atomicAdd(&cnt[e], 1);
            tl_tok[e*NTOK + pos] = t;
            tl_w[e*NTOK + pos] = w[s]*inv*RSCALE;   // fold routed-output scale
        }
    }
}

__global__ void scan_kernel(const int* __restrict__ cnt, int* __restrict__ off) {
    if (threadIdx.x == 0) {
        int s = 0;
        for (int e = 0; e < NEXP; ++e) { off[e] = s; s += cnt[e]; }
    }
}

// ---------------- fused gate/up GEMM + silu*up ----------------
// block: 256 thr; tile [64 rows][64 cols]; K chunks of 16; each thread 4x4 outputs (x2 for g,u)
template<bool GATHER>
__global__ __launch_bounds__(256) void gateup_kernel(
    const float* __restrict__ x,     // [NTOK][HIDN]
    const float* __restrict__ Wg,    // GATHER: [E][K][J] else [K][J]
    const float* __restrict__ Wu,
    float* __restrict__ H,           // GATHER: compact rows [*][J] else [NTOK][J]
    const int* __restrict__ cnt, const int* __restrict__ off,
    const int* __restrict__ tl_tok,
    int K, int J)
{
    const int e  = blockIdx.x;
    const int nrow = GATHER ? cnt[e] : NTOK;
    const int row0 = blockIdx.y * 64;
    if (row0 >= nrow) return;
    const int jbase = blockIdx.z * 64;
    const int tid = threadIdx.x;

    __shared__ float xs[16][68];
    __shared__ float gs[16][68];
    __shared__ float us[16][68];
    __shared__ int toks[64];

    if (tid < 64) {
        int lt = row0 + tid;
        int tok;
        if (GATHER) tok = (lt < nrow) ? tl_tok[e*NTOK + lt] : 0;
        else        tok = (lt < nrow) ? lt : 0;
        toks[tid] = tok;
    }
    __syncthreads();

    const float* wg = Wg + (GATHER ? (size_t)e*K*J : (size_t)0);
    const float* wu = Wu + (GATHER ? (size_t)e*K*J : (size_t)0);

    const int j0 = (tid & 15) * 4;       // 0..60
    const int r0 = (tid >> 4) * 4;       // 0..60
    const int lx_r = tid >> 2;           // 0..63
    const int lx_k = (tid & 3) * 4;      // 0,4,8,12
    const int lw_k = tid >> 4;           // 0..15
    const int lw_j = (tid & 15) * 4;     // 0..60
    const size_t xrow = (size_t)toks[lx_r] * HIDN;

    float accg[4][4] = {};
    float accu[4][4] = {};

    for (int k0 = 0; k0 < K; k0 += 16) {
        // stage x^T chunk
        {
            float4 v = *(const float4*)(x + xrow + k0 + lx_k);
            xs[lx_k+0][lx_r] = v.x; xs[lx_k+1][lx_r] = v.y;
            xs[lx_k+2][lx_r] = v.z; xs[lx_k+3][lx_r] = v.w;
        }
        // stage W chunks
        {
            size_t wroff = (size_t)(k0 + lw_k) * J + jbase + lw_j;
            *(float4*)&gs[lw_k][lw_j] = *(const float4*)(wg + wroff);
            *(float4*)&us[lw_k][lw_j] = *(const float4*)(wu + wroff);
        }
        __syncthreads();
        #pragma unroll
        for (int kk = 0; kk < 16; ++kk) {
            float4 av = *(const float4*)&xs[kk][r0];
            float4 bg = *(const float4*)&gs[kk][j0];
            float4 bu = *(const float4*)&us[kk][j0];
            const float a4[4] = {av.x, av.y, av.z, av.w};
            const float g4[4] = {bg.x, bg.y, bg.z, bg.w};
            const float u4[4] = {bu.x, bu.y, bu.z, bu.w};
            #pragma unroll
            for (int r = 0; r < 4; ++r)
                #pragma unroll
                for (int jj = 0; jj < 4; ++jj) {
                    accg[r][jj] += a4[r] * g4[jj];
                    accu[r][jj] += a4[r] * u4[jj];
                }
        }
        __syncthreads();
    }

    const int offE = GATHER ? off[e] : 0;
    #pragma unroll
    for (int r = 0; r < 4; ++r) {
        int lrow = row0 + r0 + r;
        if (lrow < nrow) {
            float4 o;
            float g, u;
            g = accg[r][0]; u = accu[r][0]; o.x = g/(1.f+expf(-g))*u;
            g = accg[r][1]; u = accu[r][1]; o.y = g/(1.f+expf(-g))*u;
            g = accg[r][2]; u = accu[r][2]; o.z = g/(1.f+expf(-g))*u;
            g = accg[r][3]; u = accu[r][3]; o.w = g/(1.f+expf(-g))*u;
            *(float4*)&H[(size_t)(offE + lrow)*J + jbase + j0] = o;
        }
    }
}

// ---------------- down GEMM (+ weighted scatter for routed path) ----------------
template<bool GATHER>
__global__ __launch_bounds__(256) void down_kernel(
    const float* __restrict__ H,     // GATHER: compact [*][K] else [NTOK][K]
    const float* __restrict__ Wd,    // GATHER: [E][K][HIDN] else [K][HIDN]
    float* __restrict__ out,         // [NTOK][HIDN]
    const int* __restrict__ cnt, const int* __restrict__ off,
    const int* __restrict__ tl_tok, const float* __restrict__ tl_w,
    int K)
{
    const int e  = blockIdx.x;
    const int nrow = GATHER ? cnt[e] : NTOK;
    const int row0 = blockIdx.y * 64;
    if (row0 >= nrow) return;
    const int jbase = blockIdx.z * 64;
    const int tid = threadIdx.x;

    __shared__ float hs[16][68];
    __shared__ float ws_[16][68];

    const int offE = GATHER ? off[e] : 0;
    const float* wd = Wd + (GATHER ? (size_t)e*K*HIDN : (size_t)0);

    const int j0 = (tid & 15) * 4;
    const int r0 = (tid >> 4) * 4;
    const int lx_r = tid >> 2;
    const int lx_k = (tid & 3) * 4;
    const int lw_k = tid >> 4;
    const int lw_j = (tid & 15) * 4;
    const size_t hrow = (size_t)(offE + row0 + lx_r) * K;   // rows past count read slack (allocated)

    float acc[4][4] = {};

    for (int k0 = 0; k0 < K; k0 += 16) {
        {
            float4 v = *(const float4*)(H + hrow + k0 + lx_k);
            hs[lx_k+0][lx_r] = v.x; hs[lx_k+1][lx_r] = v.y;
            hs[lx_k+2][lx_r] = v.z; hs[lx_k+3][lx_r] = v.w;
        }
        {
            size_t wroff = (size_t)(k0 + lw_k) * HIDN + jbase + lw_j;
            *(float4*)&ws_[lw_k][lw_j] = *(const float4*)(wd + wroff);
        }
        __syncthreads();
        #pragma unroll
        for (int kk = 0; kk < 16; ++kk) {
            float4 av = *(const float4*)&hs[kk][r0];
            float4 bv = *(const float4*)&ws_[kk][j0];
            const float a4[4] = {av.x, av.y, av.z, av.w};
            const float b4[4] = {bv.x, bv.y, bv.z, bv.w};
            #pragma unroll
            for (int r = 0; r < 4; ++r)
                #pragma unroll
                for (int jj = 0; jj < 4; ++jj)
                    acc[r][jj] += a4[r] * b4[jj];
        }
        __syncthreads();
    }

    #pragma unroll
    for (int r = 0; r < 4; ++r) {
        int lrow = row0 + r0 + r;
        if (lrow < nrow) {
            if (GATHER) {
                int tok = tl_tok[e*NTOK + lrow];
                float wgt = tl_w[e*NTOK + lrow];
                float* op = out + (size_t)tok*HIDN + jbase + j0;
                atomicAdd(op+0, acc[r][0]*wgt);
                atomicAdd(op+1, acc[r][1]*wgt);
                atomicAdd(op+2, acc[r][2]*wgt);
                atomicAdd(op+3, acc[r][3]*wgt);
            } else {
                float4 o; o.x = acc[r][0]; o.y = acc[r][1]; o.z = acc[r][2]; o.w = acc[r][3];
                *(float4*)&out[(size_t)lrow*HIDN + jbase + j0] = o;
            }
        }
    }
}

extern "C" void kernel_launch(void* const* d_in, const int* in_sizes, int n_in,
                              void* d_out, int out_size, void* d_ws, size_t ws_size,
                              hipStream_t stream) {
    const float* x       = (const float*)d_in[0];
    const float* gate_w  = (const float*)d_in[1];
    const float* s_bias  = (const float*)d_in[2];
    const float* w_gate  = (const float*)d_in[3];
    const float* w_up    = (const float*)d_in[4];
    const float* w_down  = (const float*)d_in[5];
    const float* sh_gate = (const float*)d_in[6];
    const float* sh_up   = (const float*)d_in[7];
    const float* sh_down = (const float*)d_in[8];
    float* outp = (float*)d_out;

    char* ws = (char*)d_ws;
    int*   cnt = (int*)(ws + WS_CNT);
    int*   off = (int*)(ws + WS_OFF);
    int*   tlt = (int*)(ws + WS_TOK);
    float* tlw = (float*)(ws + WS_W);
    float* H   = (float*)(ws + WS_H);
    float* HS  = (float*)(ws + WS_HS);

    zero_cnt_kernel<<<1, 64, 0, stream>>>(cnt);
    routing_kernel<<<NTOK, 64, 0, stream>>>(x, gate_w, s_bias, cnt, tlt, tlw);
    scan_kernel<<<1, 64, 0, stream>>>(cnt, off);

    // routed gate/up: grid (expert, token-tile, j-tile)
    gateup_kernel<true><<<dim3(NEXP, NTOK/64, INTERD/64), 256, 0, stream>>>(
        x, w_gate, w_up, H, cnt, off, tlt, HIDN, INTERD);
    // shared gate/up
    gateup_kernel<false><<<dim3(1, NTOK/64, SHINTER/64), 256, 0, stream>>>(
        x, sh_gate, sh_up, HS, cnt, off, tlt, HIDN, SHINTER);
    // shared down writes out (must precede routed scatter-add)
    down_kernel<false><<<dim3(1, NTOK/64, HIDN/64), 256, 0, stream>>>(
        HS, sh_down, outp, cnt, off, tlt, tlw, SHINTER);
    // routed down: weighted atomic scatter-add
    down_kernel<true><<<dim3(NEXP, NTOK/64, HIDN/64), 256, 0, stream>>>(
        H, w_down, outp, cnt, off, tlt, tlw, INTERD);
}

// Round 2
// 1012.387 us; speedup vs baseline: 2.0340x; 2.0340x over previous
//
#include <hip/hip_runtime.h>
#include <cmath>

// DeepSeek V2 MoE — bf16-MFMA round.
// routing (fp32) -> token lists -> x->bf16 -> gathered gate/up MFMA GEMM ->
// down MFMA GEMM with weighted atomic scatter. Weights converted fp32->bf16
// inline during LDS staging (transpose to [n][k], XOR-swizzled 16B granules).

#define HIDN   1024
#define NEXP   64
#define INTERD 704
#define TOPK   6
#define NGRP   8
#define TOPG   4
#define NTOK   2048
#define SHINTER 1408
#define RSCALE 2.5f
#define FMAXV  3.402823466e38f

typedef unsigned short ushort_t;
typedef unsigned int   uint32;
using short8  = __attribute__((ext_vector_type(8))) short;
using float4v = __attribute__((ext_vector_type(4))) float;

// ---- workspace layout (bytes) ----
#define WS_CNT 0
#define WS_OFF 1024
#define WS_TOK 4096                                  // 64*2048 int
#define WS_W   (WS_TOK + NEXP*NTOK*4)                // 64*2048 float
#define WS_XB  (WS_W + NEXP*NTOK*4)                  // 2048*1024 bf16 (4MB)
#define WS_H   (WS_XB + NTOK*HIDN*2)                 // (12288+64)*704 bf16
#define WS_HS  (WS_H + (NTOK*TOPK+64)*INTERD*2)      // 2048*1408 bf16
// total ~28 MB

__device__ __forceinline__ ushort_t f2bf(float f) {
    uint32 u = __float_as_uint(f);
    u += 0x7FFFu + ((u >> 16) & 1u);     // RNE
    return (ushort_t)(u >> 16);
}
__device__ __forceinline__ int swzB(int n) { return (n ^ (n >> 3)) & 7; }

__global__ __launch_bounds__(64) void zero_cnt_kernel(int* cnt) {
    cnt[threadIdx.x] = 0;
}

// ---------------- x fp32 -> bf16 ----------------
__global__ __launch_bounds__(256) void cvtx_kernel(const float* __restrict__ x,
                                                   ushort_t* __restrict__ xb) {
    size_t i = (size_t)blockIdx.x * 1024 + threadIdx.x * 4;
    float4 v = *(const float4*)(x + i);
    ushort4 o;
    o.x = f2bf(v.x); o.y = f2bf(v.y); o.z = f2bf(v.z); o.w = f2bf(v.w);
    *(ushort4*)(xb + i) = o;
}

// ---------------- routing (fp32, unchanged from R1 — verified correct) ----------------
__global__ __launch_bounds__(64) void routing_kernel(
    const float* __restrict__ x, const float* __restrict__ gw,
    const float* __restrict__ bias, int* __restrict__ cnt,
    int* __restrict__ tl_tok, float* __restrict__ tl_w)
{
    __shared__ float xs[HIDN];
    __shared__ float ssc[NEXP];
    __shared__ float sscore[NEXP];
    const int t = blockIdx.x;
    const int tid = threadIdx.x;
    for (int i = tid; i < HIDN; i += 64) xs[i] = x[(size_t)t*HIDN + i];
    __syncthreads();

    const float* gwe = gw + (size_t)tid*HIDN;
    float acc = 0.f;
    for (int k = 0; k < HIDN; k += 4) {
        float4 g = *(const float4*)(gwe + k);
        acc += xs[k]*g.x + xs[k+1]*g.y + xs[k+2]*g.z + xs[k+3]*g.w;
    }
    float score = 1.f/(1.f + expf(-acc));
    sscore[tid] = score;
    ssc[tid] = score + bias[tid];
    __syncthreads();

    if (tid == 0) {
        float gsc[NGRP];
        #pragma unroll
        for (int g = 0; g < NGRP; ++g) {
            float m1 = -FMAXV, m2 = -FMAXV;
            #pragma unroll
            for (int i = 0; i < 8; ++i) {
                float v = ssc[g*8 + i];
                if (v > m1) { m2 = m1; m1 = v; }
                else if (v > m2) { m2 = v; }
            }
            gsc[g] = m1 + m2;
        }
        unsigned gselmask = 0;
        #pragma unroll
        for (int it = 0; it < TOPG; ++it) {
            float best = -FMAXV; int bg = 0;
            #pragma unroll
            for (int g = 0; g < NGRP; ++g) {
                if ((gselmask >> g) & 1u) continue;
                if (gsc[g] > best) { best = gsc[g]; bg = g; }
            }
            gselmask |= (1u << bg);
        }
        unsigned long long taken = 0ull;
        int ids[TOPK]; float w[TOPK]; float wsum = 0.f;
        #pragma unroll
        for (int it = 0; it < TOPK; ++it) {
            float best = -FMAXV; int be = 0;
            for (int e = 0; e < NEXP; ++e) {
                if (!((gselmask >> (e >> 3)) & 1u)) continue;
                if ((taken >> e) & 1ull) continue;
                float v = ssc[e];
                if (v > best) { best = v; be = e; }
            }
            taken |= (1ull << be);
            ids[it] = be;
            w[it] = sscore[be];
            wsum += w[it];
        }
        float inv = 1.f / wsum;
        #pragma unroll
        for (int s = 0; s < TOPK; ++s) {
            int e = ids[s];
            int pos = atomicAdd(&cnt[e], 1);
            tl_tok[e*NTOK + pos] = t;
            tl_w[e*NTOK + pos] = w[s]*inv*RSCALE;
        }
    }
}

__global__ void scan_kernel(const int* __restrict__ cnt, int* __restrict__ off) {
    if (threadIdx.x == 0) {
        int s = 0;
        for (int e = 0; e < NEXP; ++e) { off[e] = s; s += cnt[e]; }
    }
}

// ---------------- fused gate/up MFMA GEMM + silu*up -> bf16 H ----------------
// block 256 = 4 waves. Tile BM=64 BN=64 BK=64; wave w owns cols [w*16,w*16+16).
// A (bf16 x) in LDS [64][64] row-major, 16B slots XOR-swizzled by (row&7).
// W (fp32) transposed+converted into LDS [n][k] bf16, slots XOR'd by swzB(n).
template<bool GATHER>
__global__ __launch_bounds__(256) void gateup_mfma(
    const ushort_t* __restrict__ xb, const float* __restrict__ Wg,
    const float* __restrict__ Wu, ushort_t* __restrict__ H,
    const int* __restrict__ cnt, const int* __restrict__ off,
    const int* __restrict__ tl_tok, int N)
{
    const int e = blockIdx.x;
    const int nrow = GATHER ? cnt[e] : NTOK;
    const int row0 = blockIdx.y * 64;
    if (row0 >= nrow) return;
    const int jbase = blockIdx.z * 64;
    const int tid = threadIdx.x;
    const int lane = tid & 63, wv = tid >> 6;
    const int lm = lane & 15, lg = lane >> 4;

    __shared__ ushort_t As[64*64];
    __shared__ ushort_t Bs[2][64*64];
    __shared__ int toks[64];

    if (tid < 64) {
        int lt = row0 + tid;
        toks[tid] = GATHER ? ((lt < nrow) ? tl_tok[e*NTOK + lt] : 0)
                           : ((lt < nrow) ? lt : 0);
    }
    __syncthreads();

    const float* wg = Wg + (GATHER ? (size_t)e*HIDN*N : (size_t)0);
    const float* wu = Wu + (GATHER ? (size_t)e*HIDN*N : (size_t)0);

    const int ar = tid >> 2;            // A row 0..63
    const int ac = tid & 3;             // slot pair
    const size_t axbase = (size_t)toks[ar]*HIDN;
    const int wk = tid >> 2;            // W k-row 0..63
    const int wc = tid & 3;             // 16-col group

    float4v accg[4], accu[4];
    #pragma unroll
    for (int i = 0; i < 4; ++i) { accg[i] = (float4v){0.f,0.f,0.f,0.f}; accu[i] = (float4v){0.f,0.f,0.f,0.f}; }

    for (int k0 = 0; k0 < HIDN; k0 += 64) {
        // stage A (bf16, coalesced 16B loads)
        #pragma unroll
        for (int j = 0; j < 2; ++j) {
            int slot = ac*2 + j;
            short8 v = *(const short8*)(xb + axbase + k0 + slot*8);
            *(short8*)&As[ar*64 + ((slot ^ (ar & 7)) * 8)] = v;
        }
        // stage W (fp32 coalesced float4 loads, transpose + cvt into Bs)
        {
            size_t gbase = (size_t)(k0 + wk)*N + jbase + wc*16;
            #pragma unroll
            for (int i = 0; i < 4; ++i) {
                float4 vg = *(const float4*)(wg + gbase + i*4);
                float4 vu = *(const float4*)(wu + gbase + i*4);
                #pragma unroll
                for (int q = 0; q < 4; ++q) {
                    int n = wc*16 + i*4 + q;
                    int idx = n*64 + (((wk >> 3) ^ swzB(n)) * 8) + (wk & 7);
                    Bs[0][idx] = f2bf(((const float*)&vg)[q]);
                    Bs[1][idx] = f2bf(((const float*)&vu)[q]);
                }
            }
        }
        __syncthreads();
        #pragma unroll
        for (int kf = 0; kf < 2; ++kf) {
            short8 bg, bu;
            {
                int n = wv*16 + lm;
                int idx = n*64 + (((kf*4 + lg) ^ swzB(n)) * 8);
                bg = *(const short8*)&Bs[0][idx];
                bu = *(const short8*)&Bs[1][idx];
            }
            #pragma unroll
            for (int mf = 0; mf < 4; ++mf) {
                int m = mf*16 + lm;
                int idx = m*64 + (((kf*4 + lg) ^ (m & 7)) * 8);
                short8 a = *(const short8*)&As[idx];
                accg[mf] = __builtin_amdgcn_mfma_f32_16x16x32_bf16(a, bg, accg[mf], 0, 0, 0);
                accu[mf] = __builtin_amdgcn_mfma_f32_16x16x32_bf16(a, bu, accu[mf], 0, 0, 0);
            }
        }
        __syncthreads();
    }

    // epilogue: silu(g)*u -> bf16, store to compact H
    const int offE = GATHER ? off[e] : 0;
    #pragma unroll
    for (int mf = 0; mf < 4; ++mf) {
        #pragma unroll
        for (int r = 0; r < 4; ++r) {
            int lrow = mf*16 + lg*4 + r;
            if (row0 + lrow < nrow) {
                float g = accg[mf][r], u = accu[mf][r];
                float h = g / (1.f + __expf(-g)) * u;
                H[(size_t)(offE + row0 + lrow)*N + jbase + wv*16 + lm] = f2bf(h);
            }
        }
    }
}

// ---------------- down MFMA GEMM (+ weighted atomic scatter for routed) ----------------
template<bool GATHER>
__global__ __launch_bounds__(256) void down_mfma(
    const ushort_t* __restrict__ Hc, const float* __restrict__ Wd,
    float* __restrict__ out,
    const int* __restrict__ cnt, const int* __restrict__ off,
    const int* __restrict__ tl_tok, const float* __restrict__ tl_w,
    int K)
{
    const int e = blockIdx.x;
    const int nrow = GATHER ? cnt[e] : NTOK;
    const int row0 = blockIdx.y * 64;
    if (row0 >= nrow) return;
    const int jbase = blockIdx.z * 64;
    const int tid = threadIdx.x;
    const int lane = tid & 63, wv = tid >> 6;
    const int lm = lane & 15, lg = lane >> 4;

    __shared__ ushort_t As[64*64];
    __shared__ ushort_t Bs[64*64];
    __shared__ int   stok[64];
    __shared__ float swt[64];

    if (GATHER && tid < 64) {
        int lt = row0 + tid;
        stok[tid] = (lt < nrow) ? tl_tok[e*NTOK + lt] : 0;
        swt[tid]  = (lt < nrow) ? tl_w[e*NTOK + lt] : 0.f;
    }
    __syncthreads();

    const int offE = GATHER ? off[e] : 0;
    const float* wd = Wd + (GATHER ? (size_t)e*K*HIDN : (size_t)0);

    const int ar = tid >> 2;
    const int ac = tid & 3;
    const size_t axbase = (size_t)(offE + row0 + ar)*K;  // compact rows (slack allocated)
    const int wk = tid >> 2;
    const int wc = tid & 3;

    float4v acc[4];
    #pragma unroll
    for (int i = 0; i < 4; ++i) acc[i] = (float4v){0.f,0.f,0.f,0.f};

    for (int k0 = 0; k0 < K; k0 += 64) {
        #pragma unroll
        for (int j = 0; j < 2; ++j) {
            int slot = ac*2 + j;
            short8 v = *(const short8*)(Hc + axbase + k0 + slot*8);
            *(short8*)&As[ar*64 + ((slot ^ (ar & 7)) * 8)] = v;
        }
        {
            size_t gbase = (size_t)(k0 + wk)*HIDN + jbase + wc*16;
            #pragma unroll
            for (int i = 0; i < 4; ++i) {
                float4 vd = *(const float4*)(wd + gbase + i*4);
                #pragma unroll
                for (int q = 0; q < 4; ++q) {
                    int n = wc*16 + i*4 + q;
                    int idx = n*64 + (((wk >> 3) ^ swzB(n)) * 8) + (wk & 7);
                    Bs[idx] = f2bf(((const float*)&vd)[q]);
                }
            }
        }
        __syncthreads();
        #pragma unroll
        for (int kf = 0; kf < 2; ++kf) {
            short8 b;
            {
                int n = wv*16 + lm;
                int idx = n*64 + (((kf*4 + lg) ^ swzB(n)) * 8);
                b = *(const short8*)&Bs[idx];
            }
            #pragma unroll
            for (int mf = 0; mf < 4; ++mf) {
                int m = mf*16 + lm;
                int idx = m*64 + (((kf*4 + lg) ^ (m & 7)) * 8);
                short8 a = *(const short8*)&As[idx];
                acc[mf] = __builtin_amdgcn_mfma_f32_16x16x32_bf16(a, b, acc[mf], 0, 0, 0);
            }
        }
        __syncthreads();
    }

    const int col = jbase + wv*16 + lm;
    #pragma unroll
    for (int mf = 0; mf < 4; ++mf) {
        #pragma unroll
        for (int r = 0; r < 4; ++r) {
            int lrow = mf*16 + lg*4 + r;
            if (row0 + lrow < nrow) {
                if (GATHER) {
                    int tok = stok[lrow];
                    float wr = swt[lrow];
                    atomicAdd(out + (size_t)tok*HIDN + col, acc[mf][r] * wr);
                } else {
                    out[(size_t)(row0 + lrow)*HIDN + col] = acc[mf][r];
                }
            }
        }
    }
}

extern "C" void kernel_launch(void* const* d_in, const int* in_sizes, int n_in,
                              void* d_out, int out_size, void* d_ws, size_t ws_size,
                              hipStream_t stream) {
    const float* x       = (const float*)d_in[0];
    const float* gate_w  = (const float*)d_in[1];
    const float* s_bias  = (const float*)d_in[2];
    const float* w_gate  = (const float*)d_in[3];
    const float* w_up    = (const float*)d_in[4];
    const float* w_down  = (const float*)d_in[5];
    const float* sh_gate = (const float*)d_in[6];
    const float* sh_up   = (const float*)d_in[7];
    const float* sh_down = (const float*)d_in[8];
    float* outp = (float*)d_out;

    char* ws = (char*)d_ws;
    int*      cnt = (int*)(ws + WS_CNT);
    int*      off = (int*)(ws + WS_OFF);
    int*      tlt = (int*)(ws + WS_TOK);
    float*    tlw = (float*)(ws + WS_W);
    ushort_t* xb  = (ushort_t*)(ws + WS_XB);
    ushort_t* H   = (ushort_t*)(ws + WS_H);
    ushort_t* HS  = (ushort_t*)(ws + WS_HS);

    zero_cnt_kernel<<<1, 64, 0, stream>>>(cnt);
    cvtx_kernel<<<NTOK, 256, 0, stream>>>(x, xb);
    routing_kernel<<<NTOK, 64, 0, stream>>>(x, gate_w, s_bias, cnt, tlt, tlw);
    scan_kernel<<<1, 64, 0, stream>>>(cnt, off);

    // routed gate/up
    gateup_mfma<true><<<dim3(NEXP, NTOK/64, INTERD/64), 256, 0, stream>>>(
        xb, w_gate, w_up, H, cnt, off, tlt, INTERD);
    // shared gate/up
    gateup_mfma<false><<<dim3(1, NTOK/64, SHINTER/64), 256, 0, stream>>>(
        xb, sh_gate, sh_up, HS, cnt, off, tlt, SHINTER);
    // shared down (plain stores, initializes out) — must precede routed scatter
    down_mfma<false><<<dim3(1, NTOK/64, HIDN/64), 256, 0, stream>>>(
        HS, sh_down, outp, cnt, off, tlt, tlw, SHINTER);
    // routed down (weighted atomic scatter-add)
    down_mfma<true><<<dim3(NEXP, NTOK/64, HIDN/64), 256, 0, stream>>>(
        H, w_down, outp, cnt, off, tlt, tlw, INTERD);
}